// Round 1
// 186.044 us; speedup vs baseline: 1.0096x; 1.0096x over previous
//
#include <hip/hip_runtime.h>
#include <cstddef>

// Problem constants
constexpr int B_ = 4, H_ = 96, W_ = 96, C_ = 192, QKVC = 576;
constexpr int NPIX = B_ * H_ * W_;           // 36864
constexpr float SCALE = 0.17677669529663689f; // 32^-0.5

typedef __attribute__((ext_vector_type(8))) short bf16x8;
typedef __attribute__((ext_vector_type(4))) float f32x4;
typedef unsigned short ushort_t;

__device__ __forceinline__ unsigned short f2bf(float f) {
    unsigned int u = __builtin_bit_cast(unsigned int, f);
    u += 0x7fffu + ((u >> 16) & 1u);       // round-to-nearest-even
    return (unsigned short)(u >> 16);
}
__device__ __forceinline__ float bf2f(unsigned short h) {
    unsigned int u = ((unsigned int)h) << 16;
    return __builtin_bit_cast(float, u);
}
__device__ __forceinline__ unsigned int pack2(unsigned short a, unsigned short b) {
    return (unsigned int)a | ((unsigned int)b << 16);
}

// ---------------------------------------------------------------------------
// convert_x: fp32 -> bf16
// ---------------------------------------------------------------------------
__global__ __launch_bounds__(256) void convert_x_kernel(
    const float* __restrict__ x, ushort_t* __restrict__ xh, int n4)
{
    int i = blockIdx.x * 256 + threadIdx.x;
    if (i >= n4) return;
    float4 v = ((const float4*)x)[i];
    uint2 p;
    p.x = pack2(f2bf(v.x), f2bf(v.y));
    p.y = pack2(f2bf(v.z), f2bf(v.w));
    ((uint2*)xh)[i] = p;
}

// ---------------------------------------------------------------------------
// convert_w: w_qkv -> wqt[576][192] bf16; w_proj -> wpt_h/wpt_l split bf16.
// ---------------------------------------------------------------------------
__global__ __launch_bounds__(256) void convert_w_kernel(
    const float* __restrict__ w_qkv, const float* __restrict__ w_proj,
    ushort_t* __restrict__ wqt, ushort_t* __restrict__ wpt_h,
    ushort_t* __restrict__ wpt_l)
{
    int idx = blockIdx.x * 256 + threadIdx.x;
    if (idx < 576 * 192) {
        int n = idx / 192, k = idx - n * 192;
        wqt[idx] = f2bf(w_qkv[(size_t)k * 576 + n]);
    } else {
        int i2 = idx - 576 * 192;
        if (i2 < 192 * 192) {
            int n = i2 / 192, k = i2 - n * 192;
            float v = w_proj[(size_t)k * 192 + n];
            unsigned short h = f2bf(v);
            wpt_h[i2] = h;
            wpt_l[i2] = f2bf(v - bf2f(h));
        }
    }
}

// ---------------------------------------------------------------------------
// MFMA bf16 GEMM, tile 64x192x64. A bf16 [M][K], B pre-transposed Bt[n][k].
// BSPLIT: 2 passes A*(Bh+Bl). OUTBF: bf16 C. VT: write the v-channels
// (local col 128..191) ONLY to vT (dim-major) -- they are never read from
// qkvh, so the strided C store for them is skipped (saves 14.2 MB writes).
// ---------------------------------------------------------------------------
template<bool BSPLIT, bool OUTBF, bool VT>
__global__ __launch_bounds__(256) void gemm_mfma2_kernel(
    const ushort_t* __restrict__ A,
    const ushort_t* __restrict__ Bt_h, const ushort_t* __restrict__ Bt_l,
    const float* __restrict__ bias, void* __restrict__ Cout,
    ushort_t* __restrict__ vTout, int M, int N, int K)
{
    constexpr int NPB = BSPLIT ? 2 : 1;
    __shared__ __align__(16) ushort_t As[8 * 64 * 8];
    __shared__ __align__(16) ushort_t Bs[NPB][8 * 192 * 8];

    const int tid = threadIdx.x;
    const int lane = tid & 63;
    const int w = tid >> 6;
    const int wm = (w & 1) * 32;
    const int wn = (w >> 1) * 96;
    const int fm = lane & 15;
    const int fq = lane >> 4;

    const int ntiles = N / 192;
    const int m0 = (blockIdx.x / ntiles) * 64;
    const int n0 = (blockIdx.x % ntiles) * 192;

    f32x4 acc[2][6];
    #pragma unroll
    for (int mi = 0; mi < 2; ++mi)
        #pragma unroll
        for (int ni = 0; ni < 6; ++ni)
            acc[mi][ni] = (f32x4){0.f, 0.f, 0.f, 0.f};

    for (int k0 = 0; k0 < K; k0 += 64) {
        __syncthreads();
        #pragma unroll
        for (int it = 0; it < 2; ++it) {
            int idx = it * 256 + tid;
            int m = idx >> 3, kc = idx & 7;
            uint4 v = *(const uint4*)(A + (size_t)(m0 + m) * K + k0 + kc * 8);
            *(uint4*)(&As[0] + (kc * 64 + (m ^ kc)) * 8) = v;
        }
        #pragma unroll
        for (int it = 0; it < 6; ++it) {
            int idx = it * 256 + tid;
            int n = idx >> 3, kc = idx & 7;
            int phys = kc * 192 + (n ^ kc);
            *(uint4*)(&Bs[0][0] + phys * 8) =
                *(const uint4*)(Bt_h + (size_t)(n0 + n) * K + k0 + kc * 8);
            if constexpr (BSPLIT)
                *(uint4*)(&Bs[NPB - 1][0] + phys * 8) =
                    *(const uint4*)(Bt_l + (size_t)(n0 + n) * K + k0 + kc * 8);
        }
        __syncthreads();

        #pragma unroll
        for (int kt2 = 0; kt2 < 2; ++kt2) {
            const int kc = kt2 * 4 + fq;
            bf16x8 ah[2], bh[6];
            #pragma unroll
            for (int mi = 0; mi < 2; ++mi)
                ah[mi] = *(const bf16x8*)(&As[0] + (kc * 64 + ((wm + mi * 16 + fm) ^ kc)) * 8);
            #pragma unroll
            for (int ni = 0; ni < 6; ++ni)
                bh[ni] = *(const bf16x8*)(&Bs[0][0] + (kc * 192 + ((wn + ni * 16 + fm) ^ kc)) * 8);
            #pragma unroll
            for (int mi = 0; mi < 2; ++mi)
                #pragma unroll
                for (int ni = 0; ni < 6; ++ni)
                    acc[mi][ni] = __builtin_amdgcn_mfma_f32_16x16x32_bf16(
                        ah[mi], bh[ni], acc[mi][ni], 0, 0, 0);
            if constexpr (BSPLIT) {
                bf16x8 bl[6];
                #pragma unroll
                for (int ni = 0; ni < 6; ++ni)
                    bl[ni] = *(const bf16x8*)(&Bs[NPB - 1][0] + (kc * 192 + ((wn + ni * 16 + fm) ^ kc)) * 8);
                #pragma unroll
                for (int mi = 0; mi < 2; ++mi)
                    #pragma unroll
                    for (int ni = 0; ni < 6; ++ni)
                        acc[mi][ni] = __builtin_amdgcn_mfma_f32_16x16x32_bf16(
                            ah[mi], bl[ni], acc[mi][ni], 0, 0, 0);
            }
        }
    }

    // epilogue: C/D col=lane&15, row=fq*4+reg
    #pragma unroll
    for (int ni = 0; ni < 6; ++ni) {
        const int lcol = wn + ni * 16 + fm;
        const int col = n0 + lcol;
        const float bv = bias[col];
        const int vl = lcol - 128;               // v-channel index (if >=0)
        #pragma unroll
        for (int mi = 0; mi < 2; ++mi) {
            const int rbase = m0 + wm + mi * 16 + fq * 4;
            #pragma unroll
            for (int r = 0; r < 4; ++r) {
                float val = acc[mi][ni][r] + bv;
                bool skipc = false;
                if constexpr (VT) {
                    if (vl >= 0) {
                        int pix = rbase + r;
                        int bb = pix / 9216;
                        int rem = pix - bb * 9216;
                        int ii = rem / 96;
                        int jj = rem - ii * 96;
                        int hh = vl >> 5, dd = vl & 31;
                        vTout[((size_t)((bb * 96 + ii) * 6) + (n0 / 192) * 2 + hh) * 3072
                              + dd * 96 + jj] = f2bf(val);
                        skipc = true;            // v never read from qkvh
                    }
                }
                if (!skipc) {
                    if constexpr (OUTBF)
                        ((ushort_t*)Cout)[(size_t)(rbase + r) * N + col] = f2bf(val);
                    else
                        ((float*)Cout)[(size_t)(rbase + r) * N + col] = val;
                }
            }
        }
    }
}

// ---------------------------------------------------------------------------
// Neighborhood attention v5 — barrier-free MFMA flash-style.
// Block = (g, h, b, row i): 2304 blocks, 384 threads = 6 waves; wave c owns
// the 16-pixel chunk j in [16c, 16c+16). KEY CHANGE vs v4: K and Vt MFMA
// B-fragments are 16B-contiguous per lane in global memory (qkv k-slices are
// 64B aligned-contiguous per pixel; vT is dim-major), so they are loaded
// per-lane directly from global (L2-served) with a one-iteration register
// prefetch. No block-wide LDS staging, NO __syncthreads at all — waves run
// independently. Only the per-wave P transpose (C-layout -> A-layout) goes
// through LDS (7.7 KB/block; wave-internal DS ordering, no barrier).
// Grid is XCD-swizzled: logical = (phys%8)*288 + phys/8 gives each XCD a
// contiguous run of 48 image rows -> K/V row reuse lands in one L2.
// ---------------------------------------------------------------------------
__global__ __launch_bounds__(384, 4) void na2d_kernel(
    const ushort_t* __restrict__ qkv, const ushort_t* __restrict__ vT,
    ushort_t* __restrict__ attn)
{
    __shared__ ushort_t Pb[6][16 * 40];    // per-wave P, [pix][pad40] swizzled

    // bijective XCD-contiguity swizzle (2304 = 8 * 288)
    int phys = blockIdx.x;
    int idx = (phys & 7) * 288 + (phys >> 3);

    const int g = idx % 3; idx /= 3;
    const int h = idx & 1; idx >>= 1;
    const int i = idx % 96;
    const int b = idx / 96;

    const int K = 7 + 2 * g, cc = K >> 1;
    int si = i - cc; if (si < 0) si = 0; if (si > H_ - K) si = H_ - K;

    const int tid = threadIdx.x;
    const int w = tid >> 6, lane = tid & 63;
    const int fm = lane & 15, fq = lane >> 4;
    const int pixbase = w * 16;

    int cb = (pixbase - cc) & ~7;          // aligned union-window base
    if (cb < 0) cb = 0; if (cb > 64) cb = 64;
    const int col0 = cb + fm, col1 = cb + 16 + fm;

    int sj[4];
    #pragma unroll
    for (int r = 0; r < 4; ++r) {
        int jj = pixbase + fq * 4 + r - cc;
        if (jj < 0) jj = 0; if (jj > W_ - K) jj = W_ - K;
        sj[r] = jj;
    }

    // Q A-frag: pixel j=pixbase+fm, dims fq*8..+8  (direct global, 16B)
    const size_t rowstride = (size_t)W_ * QKVC;    // ushorts per image row
    const bf16x8 qfrag = *(const bf16x8*)(
        qkv + (size_t)(b * H_ + i) * rowstride + (size_t)(pixbase + fm) * QKVC
        + g * 192 + h * 32 + fq * 8);

    // per-lane fragment pointers (advance by one image row per t)
    const ushort_t* kp0 = qkv + (size_t)(b * H_ + si) * rowstride
        + (size_t)col0 * QKVC + g * 192 + 64 + h * 32 + fq * 8;
    const ushort_t* kp1 = kp0 + (size_t)16 * QKVC;     // col1 = col0 + 16
    const size_t vslice = ((size_t)((b * H_ + si) * 6) + g * 2 + h) * 3072;
    const ushort_t* vp0 = vT + vslice + (size_t)fm * 96 + cb + fq * 8;
    const ushort_t* vp1 = vp0 + 16 * 96;

    f32x4 y0 = {0.f, 0.f, 0.f, 0.f}, y1 = {0.f, 0.f, 0.f, 0.f};
    float lacc[4] = {0.f, 0.f, 0.f, 0.f};

    bf16x8 kf0 = *(const bf16x8*)kp0;
    bf16x8 kf1 = *(const bf16x8*)kp1;
    bf16x8 vf0 = *(const bf16x8*)vp0;
    bf16x8 vf1 = *(const bf16x8*)vp1;

    for (int t = 0; t < K; ++t) {
        const bf16x8 ck0 = kf0, ck1 = kf1, cv0 = vf0, cv1 = vf1;
        if (t + 1 < K) {                   // register prefetch of next row
            kp0 += rowstride; kp1 += rowstride;
            vp0 += 18432;     vp1 += 18432;
            kf0 = *(const bf16x8*)kp0;
            kf1 = *(const bf16x8*)kp1;
            vf0 = *(const bf16x8*)vp0;
            vf1 = *(const bf16x8*)vp1;
        }

        // ---- S = Q·K^T (2 col-tiles) ----
        f32x4 s0 = __builtin_amdgcn_mfma_f32_16x16x32_bf16(
            qfrag, ck0, (f32x4){0.f, 0.f, 0.f, 0.f}, 0, 0, 0);
        f32x4 s1 = __builtin_amdgcn_mfma_f32_16x16x32_bf16(
            qfrag, ck1, (f32x4){0.f, 0.f, 0.f, 0.f}, 0, 0, 0);

        // ---- mask, exp, P write (C-layout -> LDS in A-frag order) ----
        #pragma unroll
        for (int r = 0; r < 4; ++r) {
            float e0 = __expf(s0[r] * SCALE);
            float e1 = __expf(s1[r] * SCALE);
            e0 = ((unsigned)(col0 - sj[r]) < (unsigned)K) ? e0 : 0.f;
            e1 = ((unsigned)(col1 - sj[r]) < (unsigned)K) ? e1 : 0.f;
            unsigned short p0 = f2bf(e0), p1 = f2bf(e1);
            lacc[r] += bf2f(p0) + bf2f(p1);
            const int m = fq * 4 + r;
            Pb[w][m * 40 + (((fm >> 3) ^ (m & 3)) << 3) + (fm & 7)] = p0;
            Pb[w][m * 40 + ((((fm >> 3) + 2) ^ (m & 3)) << 3) + (fm & 7)] = p1;
        }

        // ---- y += P·V (2 dim-tiles) ----
        bf16x8 pf = *(const bf16x8*)&Pb[w][fm * 40 + ((fq ^ (fm & 3)) << 3)];
        y0 = __builtin_amdgcn_mfma_f32_16x16x32_bf16(pf, cv0, y0, 0, 0, 0);
        y1 = __builtin_amdgcn_mfma_f32_16x16x32_bf16(pf, cv1, y1, 0, 0, 0);
    }

    // ---- l reduce over the 16 col-lanes, normalize, store bf16 ----
    #pragma unroll
    for (int r = 0; r < 4; ++r) {
        float l = lacc[r];
        l += __shfl_xor(l, 1); l += __shfl_xor(l, 2);
        l += __shfl_xor(l, 4); l += __shfl_xor(l, 8);
        const float inv = 1.f / l;
        const int j = pixbase + fq * 4 + r;
        const size_t o = (size_t)((b * H_ + i) * W_ + j) * C_ + g * 64 + h * 32 + fm;
        attn[o]      = f2bf(y0[r] * inv);
        attn[o + 16] = f2bf(y1[r] * inv);
    }
}

// ---------------------------------------------------------------------------
extern "C" void kernel_launch(void* const* d_in, const int* in_sizes, int n_in,
                              void* d_out, int out_size, void* d_ws, size_t ws_size,
                              hipStream_t stream)
{
    const float* x      = (const float*)d_in[0];
    const float* w_qkv  = (const float*)d_in[1];
    const float* b_qkv  = (const float*)d_in[2];
    const float* w_proj = (const float*)d_in[3];
    const float* b_proj = (const float*)d_in[4];
    float* out = (float*)d_out;

    // Workspace: [qkvh 42.5MB][xh/attn bf16 14.2MB aliased][weights][vT 14.2MB]
    char* ws = (char*)d_ws;
    ushort_t* qkvh  = (ushort_t*)ws;
    char*     reg1  = ws + (size_t)NPIX * QKVC * 2;
    ushort_t* xh    = (ushort_t*)reg1;            // dead after GEMM1
    ushort_t* attn  = (ushort_t*)reg1;            // aliases xh
    char*     wbase = reg1 + (size_t)NPIX * C_ * 2;
    ushort_t* wqt   = (ushort_t*)wbase;
    ushort_t* wpt_h = (ushort_t*)(wbase + 576 * 192 * 2);
    ushort_t* wpt_l = (ushort_t*)(wbase + 576 * 192 * 2 + 192 * 192 * 2);
    ushort_t* vT    = (ushort_t*)(wbase + 576 * 192 * 2 + 2 * 192 * 192 * 2);

    convert_x_kernel<<<(NPIX * C_ / 4 + 255) / 256, 256, 0, stream>>>(
        x, xh, NPIX * C_ / 4);
    convert_w_kernel<<<(576 * 192 + 192 * 192 + 255) / 256, 256, 0, stream>>>(
        w_qkv, w_proj, wqt, wpt_h, wpt_l);

    // 1) qkv = x @ w_qkv + b_qkv (bf16 out, q/k only) + transposed v copy (vT)
    gemm_mfma2_kernel<false, true, true><<<(NPIX / 64) * (QKVC / 192), 256, 0, stream>>>(
        xh, wqt, nullptr, b_qkv, qkvh, vT, NPIX, QKVC, C_);

    // 2) neighborhood attention (MFMA, barrier-free): (g,h,b,i) blocks
    na2d_kernel<<<2304, 384, 0, stream>>>(qkvh, vT, attn);

    // 3) out = attn @ w_proj + b_proj (A bf16, B split-bf16 2-pass)
    gemm_mfma2_kernel<true, false, false><<<(NPIX / 64) * (C_ / 192), 256, 0, stream>>>(
        attn, wpt_h, wpt_l, b_proj, out, nullptr, NPIX, C_, C_);
}

// Round 3
// 161.061 us; speedup vs baseline: 1.1662x; 1.1551x over previous
//
#include <hip/hip_runtime.h>
#include <cstddef>

// Problem constants
constexpr int B_ = 4, H_ = 96, W_ = 96, C_ = 192, QKVC = 576;
constexpr int NPIX = B_ * H_ * W_;           // 36864
// exp(s*SCALE) = 2^(s*C2), C2 = 32^-0.5 * log2(e)
constexpr float C2 = 0.25503486208385085f;

typedef __attribute__((ext_vector_type(8))) short bf16x8;
typedef __attribute__((ext_vector_type(4))) float f32x4;
typedef unsigned short ushort_t;

__device__ __forceinline__ unsigned short f2bf(float f) {
    unsigned int u = __builtin_bit_cast(unsigned int, f);
    u += 0x7fffu + ((u >> 16) & 1u);       // round-to-nearest-even
    return (unsigned short)(u >> 16);
}
__device__ __forceinline__ float bf2f(unsigned short h) {
    unsigned int u = ((unsigned int)h) << 16;
    return __builtin_bit_cast(float, u);
}
__device__ __forceinline__ unsigned int pack2(unsigned short a, unsigned short b) {
    return (unsigned int)a | ((unsigned int)b << 16);
}
__device__ __forceinline__ float fexp2(float x) {
#if __has_builtin(__builtin_amdgcn_exp2f)
    return __builtin_amdgcn_exp2f(x);
#else
    return __expf(x * 0.6931471805599453f);
#endif
}

// ---------------------------------------------------------------------------
// convert_x: fp32 -> bf16
// ---------------------------------------------------------------------------
__global__ __launch_bounds__(256) void convert_x_kernel(
    const float* __restrict__ x, ushort_t* __restrict__ xh, int n4)
{
    int i = blockIdx.x * 256 + threadIdx.x;
    if (i >= n4) return;
    float4 v = ((const float4*)x)[i];
    uint2 p;
    p.x = pack2(f2bf(v.x), f2bf(v.y));
    p.y = pack2(f2bf(v.z), f2bf(v.w));
    ((uint2*)xh)[i] = p;
}

// ---------------------------------------------------------------------------
// convert_w: w_qkv -> wqt[576][192] bf16; w_proj -> wpt_h/wpt_l split bf16.
// ---------------------------------------------------------------------------
__global__ __launch_bounds__(256) void convert_w_kernel(
    const float* __restrict__ w_qkv, const float* __restrict__ w_proj,
    ushort_t* __restrict__ wqt, ushort_t* __restrict__ wpt_h,
    ushort_t* __restrict__ wpt_l)
{
    int idx = blockIdx.x * 256 + threadIdx.x;
    if (idx < 576 * 192) {
        int n = idx / 192, k = idx - n * 192;
        wqt[idx] = f2bf(w_qkv[(size_t)k * 576 + n]);
    } else {
        int i2 = idx - 576 * 192;
        if (i2 < 192 * 192) {
            int n = i2 / 192, k = i2 - n * 192;
            float v = w_proj[(size_t)k * 192 + n];
            unsigned short h = f2bf(v);
            wpt_h[i2] = h;
            wpt_l[i2] = f2bf(v - bf2f(h));
        }
    }
}

// ---------------------------------------------------------------------------
// MFMA bf16 GEMM, tile 64xNTx64. A bf16 [M][K], B pre-transposed Bt[n][k].
// BSPLIT: 2 passes A*(Bh+Bl). OUTBF: bf16 C. VT: write the v-channels
// (local col 128..191, requires NT=192) ONLY to vT (dim-major), packed as
// one 8B store per fragment (4 consecutive jj at fixed dd).
// Grid is XCD-swizzled (gridDim.x must be a multiple of 8).
// ---------------------------------------------------------------------------
template<bool BSPLIT, bool OUTBF, bool VT, int NT>
__global__ __launch_bounds__(256) void gemm_mfma2_kernel(
    const ushort_t* __restrict__ A,
    const ushort_t* __restrict__ Bt_h, const ushort_t* __restrict__ Bt_l,
    const float* __restrict__ bias, void* __restrict__ Cout,
    ushort_t* __restrict__ vTout, int M, int N, int K)
{
    constexpr int NPB = BSPLIT ? 2 : 1;
    constexpr int NI = NT / 32;            // 16-wide frags per wave (n-dim)
    __shared__ __align__(16) ushort_t As[8 * 64 * 8];
    __shared__ __align__(16) ushort_t Bs[NPB][8 * NT * 8];

    const int tid = threadIdx.x;
    const int lane = tid & 63;
    const int w = tid >> 6;
    const int wm = (w & 1) * 32;
    const int wn = (w >> 1) * (NT / 2);
    const int fm = lane & 15;
    const int fq = lane >> 4;

    // bijective XCD-contiguity swizzle
    const int phys = blockIdx.x;
    const int bid = (phys & 7) * (int)(gridDim.x >> 3) + (phys >> 3);
    const int ntiles = N / NT;
    const int m0 = (bid / ntiles) * 64;
    const int n0 = (bid % ntiles) * NT;

    f32x4 acc[2][NI];
    #pragma unroll
    for (int mi = 0; mi < 2; ++mi)
        #pragma unroll
        for (int ni = 0; ni < NI; ++ni)
            acc[mi][ni] = (f32x4){0.f, 0.f, 0.f, 0.f};

    for (int k0 = 0; k0 < K; k0 += 64) {
        __syncthreads();
        #pragma unroll
        for (int it = 0; it < 2; ++it) {
            int idx = it * 256 + tid;
            int m = idx >> 3, kc = idx & 7;
            uint4 v = *(const uint4*)(A + (size_t)(m0 + m) * K + k0 + kc * 8);
            *(uint4*)(&As[0] + (kc * 64 + (m ^ kc)) * 8) = v;
        }
        #pragma unroll
        for (int it = 0; it < NI; ++it) {
            int idx = it * 256 + tid;
            int n = idx >> 3, kc = idx & 7;
            int phys_g = kc * NT + (n ^ kc);
            *(uint4*)(&Bs[0][0] + phys_g * 8) =
                *(const uint4*)(Bt_h + (size_t)(n0 + n) * K + k0 + kc * 8);
            if constexpr (BSPLIT)
                *(uint4*)(&Bs[NPB - 1][0] + phys_g * 8) =
                    *(const uint4*)(Bt_l + (size_t)(n0 + n) * K + k0 + kc * 8);
        }
        __syncthreads();

        #pragma unroll
        for (int kt2 = 0; kt2 < 2; ++kt2) {
            const int kc = kt2 * 4 + fq;
            bf16x8 ah[2], bh[NI];
            #pragma unroll
            for (int mi = 0; mi < 2; ++mi)
                ah[mi] = *(const bf16x8*)(&As[0] + (kc * 64 + ((wm + mi * 16 + fm) ^ kc)) * 8);
            #pragma unroll
            for (int ni = 0; ni < NI; ++ni)
                bh[ni] = *(const bf16x8*)(&Bs[0][0] + (kc * NT + ((wn + ni * 16 + fm) ^ kc)) * 8);
            #pragma unroll
            for (int mi = 0; mi < 2; ++mi)
                #pragma unroll
                for (int ni = 0; ni < NI; ++ni)
                    acc[mi][ni] = __builtin_amdgcn_mfma_f32_16x16x32_bf16(
                        ah[mi], bh[ni], acc[mi][ni], 0, 0, 0);
            if constexpr (BSPLIT) {
                bf16x8 bl[NI];
                #pragma unroll
                for (int ni = 0; ni < NI; ++ni)
                    bl[ni] = *(const bf16x8*)(&Bs[NPB - 1][0] + (kc * NT + ((wn + ni * 16 + fm) ^ kc)) * 8);
                #pragma unroll
                for (int mi = 0; mi < 2; ++mi)
                    #pragma unroll
                    for (int ni = 0; ni < NI; ++ni)
                        acc[mi][ni] = __builtin_amdgcn_mfma_f32_16x16x32_bf16(
                            ah[mi], bl[ni], acc[mi][ni], 0, 0, 0);
            }
        }
    }

    // epilogue: C/D col=lane&15, row=fq*4+reg
    #pragma unroll
    for (int ni = 0; ni < NI; ++ni) {
        const int lcol = wn + ni * 16 + fm;
        const int col = n0 + lcol;
        const float bv = bias[col];
        const int vl = lcol - 128;               // v-channel index (if >=0)
        #pragma unroll
        for (int mi = 0; mi < 2; ++mi) {
            const int rbase = m0 + wm + mi * 16 + fq * 4;
            if constexpr (VT) {
                if (vl >= 0) {
                    // 4 r-values are 4 consecutive jj at fixed dd: one 8B store.
                    // rbase is 4-aligned and 96 % 4 == 0 -> never crosses a row.
                    int bb = rbase / 9216;
                    int rem = rbase - bb * 9216;
                    int ii = rem / 96;
                    int jj = rem - ii * 96;
                    int hh = vl >> 5, dd = vl & 31;
                    unsigned long long pk =
                          (unsigned long long)f2bf(acc[mi][ni][0] + bv)
                        | ((unsigned long long)f2bf(acc[mi][ni][1] + bv) << 16)
                        | ((unsigned long long)f2bf(acc[mi][ni][2] + bv) << 32)
                        | ((unsigned long long)f2bf(acc[mi][ni][3] + bv) << 48);
                    *(unsigned long long*)(vTout
                        + ((size_t)((bb * 96 + ii) * 6) + (n0 / 192) * 2 + hh) * 3072
                        + (size_t)dd * 96 + jj) = pk;
                    continue;                    // v never read from qkvh
                }
            }
            #pragma unroll
            for (int r = 0; r < 4; ++r) {
                float val = acc[mi][ni][r] + bv;
                if constexpr (OUTBF)
                    ((ushort_t*)Cout)[(size_t)(rbase + r) * N + col] = f2bf(val);
                else
                    ((float*)Cout)[(size_t)(rbase + r) * N + col] = val;
            }
        }
    }
}

// ---------------------------------------------------------------------------
// Neighborhood attention v4b — MFMA flash-style (verified R0 structure)
// + XCD-bijective grid swizzle + mask folded into exp2 bias (no cndmask).
// Block = (g, h, b, row i): 2304 blocks, 384 threads = 6 waves; wave c owns
// the 16-pixel chunk j in [16c, 16c+16). Per window row t (K of them):
//   S[16x32] = Q·K^T via 2x mfma over the chunk's 32-col union window;
//   e = 2^(S*C2 + bias) with bias in {0, -1e30} (masked -> exactly 0);
//   P through per-wave LDS (C-layout -> A-layout); y += P·V via 2x mfma
//   with B-frags from Vt (dim-major V, from GEMM1's epilogue).
// K/Vt staged double-buffered with register prefetch.
// ---------------------------------------------------------------------------
__global__ __launch_bounds__(384, 5) void na2d_kernel(
    const ushort_t* __restrict__ qkv, const ushort_t* __restrict__ vT,
    ushort_t* __restrict__ attn)
{
    __shared__ ushort_t Kb[2][96 * 40];    // [col][pad40], chunk-XOR swizzle
    __shared__ ushort_t Vtb[2][32 * 104];  // [dim][pad104]
    __shared__ ushort_t Pb[6][16 * 40];    // per-wave P, [pix][pad40] swizzled

    // bijective XCD-contiguity swizzle (2304 = 8 * 288)
    int phys = blockIdx.x;
    int idx = (phys & 7) * 288 + (phys >> 3);

    const int g = idx % 3; idx /= 3;       // g fastest: XCD load balance
    const int h = idx & 1; idx >>= 1;
    const int i = idx % 96;
    const int b = idx / 96;

    const int K = 7 + 2 * g, cc = K >> 1;
    int si = i - cc; if (si < 0) si = 0; if (si > H_ - K) si = H_ - K;

    const int tid = threadIdx.x;
    const int w = tid >> 6, lane = tid & 63;
    const int fm = lane & 15, fq = lane >> 4;
    const int pixbase = w * 16;

    int cb = (pixbase - cc) & ~7;          // aligned union-window base
    if (cb < 0) cb = 0; if (cb > 64) cb = 64;
    const int col0 = cb + fm, col1 = cb + 16 + fm;

    // per-(lane,r) softmax mask -> exp2 bias (loop-invariant)
    float bm0[4], bm1[4];
    #pragma unroll
    for (int r = 0; r < 4; ++r) {
        int jj = pixbase + fq * 4 + r - cc;
        if (jj < 0) jj = 0; if (jj > W_ - K) jj = W_ - K;
        bm0[r] = ((unsigned)(col0 - jj) < (unsigned)K) ? 0.f : -1e30f;
        bm1[r] = ((unsigned)(col1 - jj) < (unsigned)K) ? 0.f : -1e30f;
    }

    // Q A-frag: pixel j=pixbase+fm, dims fq*8..+8
    const size_t rowstride = (size_t)W_ * QKVC;    // ushorts per image row
    const bf16x8 qfrag = *(const bf16x8*)(
        qkv + (size_t)(b * H_ + i) * rowstride + (size_t)(pixbase + fm) * QKVC
        + g * 192 + h * 32 + fq * 8);

    // staging maps (coalesced: addr = base + tid*16B for both)
    const int scol = tid >> 2, sch = tid & 3;
    const size_t kgoff = (size_t)scol * QKVC + g * 192 + 64 + h * 32 + sch * 8;
    const int klds = scol * 40 + ((sch ^ (scol & 3)) << 3);
    const int vd = tid / 12, vc8 = tid - vd * 12;
    const int vlds = vd * 104 + vc8 * 8;
    const size_t vslice = ((size_t)((b * H_ + si) * 6) + g * 2 + h) * 3072;

    f32x4 y0 = {0.f, 0.f, 0.f, 0.f}, y1 = {0.f, 0.f, 0.f, 0.f};
    float lacc[4] = {0.f, 0.f, 0.f, 0.f};

    uint4 kv = *(const uint4*)(qkv + (size_t)(b * H_ + si) * rowstride + kgoff);
    uint4 vv = *(const uint4*)(vT + vslice + (size_t)tid * 8);

    for (int t = 0; t < K; ++t) {
        *(uint4*)&Kb[t & 1][klds] = kv;
        *(uint4*)&Vtb[t & 1][vlds] = vv;
        if (t + 1 < K) {
            kv = *(const uint4*)(qkv + (size_t)(b * H_ + si + t + 1) * rowstride + kgoff);
            vv = *(const uint4*)(vT + vslice + (size_t)(t + 1) * 18432 + (size_t)tid * 8);
        }
        __syncthreads();

        // ---- S = Q·K^T (2 col-tiles) ----
        bf16x8 kf0 = *(const bf16x8*)&Kb[t & 1][col0 * 40 + ((fq ^ (col0 & 3)) << 3)];
        bf16x8 kf1 = *(const bf16x8*)&Kb[t & 1][col1 * 40 + ((fq ^ (col1 & 3)) << 3)];
        f32x4 s0 = __builtin_amdgcn_mfma_f32_16x16x32_bf16(
            qfrag, kf0, (f32x4){0.f, 0.f, 0.f, 0.f}, 0, 0, 0);
        f32x4 s1 = __builtin_amdgcn_mfma_f32_16x16x32_bf16(
            qfrag, kf1, (f32x4){0.f, 0.f, 0.f, 0.f}, 0, 0, 0);

        // ---- e = 2^(s*C2 + bias), P write (C-layout -> LDS in A-frag order) ----
        #pragma unroll
        for (int r = 0; r < 4; ++r) {
            float e0 = fexp2(fmaf(s0[r], C2, bm0[r]));
            float e1 = fexp2(fmaf(s1[r], C2, bm1[r]));
            unsigned short p0 = f2bf(e0), p1 = f2bf(e1);
            lacc[r] += bf2f(p0) + bf2f(p1);
            const int m = fq * 4 + r;
            Pb[w][m * 40 + (((fm >> 3) ^ (m & 3)) << 3) + (fm & 7)] = p0;
            Pb[w][m * 40 + ((((fm >> 3) + 2) ^ (m & 3)) << 3) + (fm & 7)] = p1;
        }

        // ---- y += P·V (2 dim-tiles) ----
        bf16x8 pf = *(const bf16x8*)&Pb[w][fm * 40 + ((fq ^ (fm & 3)) << 3)];
        bf16x8 vf0 = *(const bf16x8*)&Vtb[t & 1][fm * 104 + cb + fq * 8];
        bf16x8 vf1 = *(const bf16x8*)&Vtb[t & 1][(16 + fm) * 104 + cb + fq * 8];
        y0 = __builtin_amdgcn_mfma_f32_16x16x32_bf16(pf, vf0, y0, 0, 0, 0);
        y1 = __builtin_amdgcn_mfma_f32_16x16x32_bf16(pf, vf1, y1, 0, 0, 0);
    }

    // ---- l reduce over the 16 col-lanes, normalize, store bf16 ----
    #pragma unroll
    for (int r = 0; r < 4; ++r) {
        float l = lacc[r];
        l += __shfl_xor(l, 1); l += __shfl_xor(l, 2);
        l += __shfl_xor(l, 4); l += __shfl_xor(l, 8);
        const float inv = 1.f / l;
        const int j = pixbase + fq * 4 + r;
        const size_t o = (size_t)((b * H_ + i) * W_ + j) * C_ + g * 64 + h * 32 + fm;
        attn[o]      = f2bf(y0[r] * inv);
        attn[o + 16] = f2bf(y1[r] * inv);
    }
}

// ---------------------------------------------------------------------------
extern "C" void kernel_launch(void* const* d_in, const int* in_sizes, int n_in,
                              void* d_out, int out_size, void* d_ws, size_t ws_size,
                              hipStream_t stream)
{
    const float* x      = (const float*)d_in[0];
    const float* w_qkv  = (const float*)d_in[1];
    const float* b_qkv  = (const float*)d_in[2];
    const float* w_proj = (const float*)d_in[3];
    const float* b_proj = (const float*)d_in[4];
    float* out = (float*)d_out;

    // Workspace: [qkvh 42.5MB][xh/attn bf16 14.2MB aliased][weights][vT 14.2MB]
    char* ws = (char*)d_ws;
    ushort_t* qkvh  = (ushort_t*)ws;
    char*     reg1  = ws + (size_t)NPIX * QKVC * 2;
    ushort_t* xh    = (ushort_t*)reg1;            // dead after GEMM1
    ushort_t* attn  = (ushort_t*)reg1;            // aliases xh
    char*     wbase = reg1 + (size_t)NPIX * C_ * 2;
    ushort_t* wqt   = (ushort_t*)wbase;
    ushort_t* wpt_h = (ushort_t*)(wbase + 576 * 192 * 2);
    ushort_t* wpt_l = (ushort_t*)(wbase + 576 * 192 * 2 + 192 * 192 * 2);
    ushort_t* vT    = (ushort_t*)(wbase + 576 * 192 * 2 + 2 * 192 * 192 * 2);

    convert_x_kernel<<<(NPIX * C_ / 4 + 255) / 256, 256, 0, stream>>>(
        x, xh, NPIX * C_ / 4);
    convert_w_kernel<<<(576 * 192 + 192 * 192 + 255) / 256, 256, 0, stream>>>(
        w_qkv, w_proj, wqt, wpt_h, wpt_l);

    // 1) qkv = x @ w_qkv + b_qkv (bf16 out, q/k only) + transposed v copy (vT)
    //    grid 1728 = 8 * 216 (XCD-swizzlable)
    gemm_mfma2_kernel<false, true, true, 192><<<(NPIX / 64) * (QKVC / 192), 256, 0, stream>>>(
        xh, wqt, nullptr, b_qkv, qkvh, vT, NPIX, QKVC, C_);

    // 2) neighborhood attention (MFMA): (g,h,b,i) blocks
    na2d_kernel<<<2304, 384, 0, stream>>>(qkvh, vT, attn);

    // 3) out = attn @ w_proj + b_proj (A bf16, B split-bf16 2-pass, N-tile 96)
    //    grid 1152 = 8 * 144
    gemm_mfma2_kernel<true, false, false, 96><<<(NPIX / 64) * (C_ / 96), 256, 0, stream>>>(
        attn, wpt_h, wpt_l, b_proj, out, nullptr, NPIX, C_, C_);
}